// Round 6
// baseline (107.197 us; speedup 1.0000x reference)
//
#include <hip/hip_runtime.h>
#include <stdint.h>

typedef float  f32x4  __attribute__((ext_vector_type(4)));
typedef __bf16 bf16x8 __attribute__((ext_vector_type(8)));
typedef __bf16 bf16x4 __attribute__((ext_vector_type(4)));

#define N_ 256
#define C_ 512
#define H_ 64
#define RS_ 32768  // row stride in transposed tensors: H_*C_ elements

__device__ __forceinline__ uint32_t pack_bf16x2(float a, float b) {
  const uint16_t ua = __builtin_bit_cast(uint16_t, (__bf16)a);
  const uint16_t ub = __builtin_bit_cast(uint16_t, (__bf16)b);
  return (uint32_t)ua | ((uint32_t)ub << 16);
}

// ---------------------------------------------------------------------------
// Pipelined transpose of FOUR p-rows: (p, 512c, 64h) fp32 -> (p, 64h, 512c)
// bf16, one 128c quarter per block. Double-buffered LDS (2 x 16 KB): while
// phase-2 of p streams out stores, the 8 global loads of p+1 are in flight.
// LDS swizzle (R5-verified, conflict-free): word L of row c stored at
// slot ((L>>1)+(c>>3) & 15)*2 + (L&1).
// ---------------------------------------------------------------------------
__device__ __forceinline__ void prep_tile4(const float* __restrict__ src,
                                           __bf16* __restrict__ dst,
                                           int pg, int qc, int t,
                                           uint32_t* lds) {
  uint32_t* bufs[2] = { lds, lds + 128 * 32 };
  const int ch0 = qc * 128;
  float4 v[8];
  auto load_regs = [&](int p) {
    const float* sb = src + ((size_t)p * 512 + ch0) * 64;
#pragma unroll
    for (int j = 0; j < 8; ++j) {
      const int fidx = j * 256 + t;
      const int c = fidx >> 4, hq = fidx & 15;
      v[j] = *reinterpret_cast<const float4*>(sb + c * 64 + hq * 4);
    }
  };
  auto lds_write = [&](uint32_t* b) {
#pragma unroll
    for (int j = 0; j < 8; ++j) {
      const int fidx = j * 256 + t;
      const int c = fidx >> 4, hq = fidx & 15;
      const int wp = (hq + (c >> 3)) & 15;
      uint2 pk;
      pk.x = pack_bf16x2(v[j].x, v[j].y);
      pk.y = pack_bf16x2(v[j].z, v[j].w);
      *reinterpret_cast<uint2*>(&b[c * 32 + wp * 2]) = pk;
    }
  };
  auto phase2 = [&](const uint32_t* bsrc, int p) {
    __bf16* db = dst + (size_t)p * RS_ + ch0;
#pragma unroll
    for (int j = 0; j < 4; ++j) {
      const int ci = j * 256 + t;
      const int cb = ci & 15, h = ci >> 4;
      const int hm = h >> 1;
      const bool odd = (h & 1) != 0;
      uint32_t W[8];
#pragma unroll
      for (int i = 0; i < 8; ++i) {
        const int c = cb * 8 + i;
        const int w = (((hm >> 1) + cb) & 15) * 2 + (hm & 1);
        W[i] = bsrc[c * 32 + w];
      }
      uint4 o;
      uint32_t* op = reinterpret_cast<uint32_t*>(&o);
#pragma unroll
      for (int k = 0; k < 4; ++k) {
        const uint32_t wa = W[2 * k], wb = W[2 * k + 1];
        op[k] = odd ? ((wa >> 16) | (wb & 0xFFFF0000u))
                    : ((wa & 0xFFFFu) | (wb << 16));
      }
      *reinterpret_cast<uint4*>(db + (size_t)h * 512 + cb * 8) = o;
    }
  };

  const int p0 = pg * 4;
  load_regs(p0);
  lds_write(bufs[0]);
  __syncthreads();
#pragma unroll
  for (int i = 0; i < 4; ++i) {
    if (i < 3) load_regs(p0 + i + 1);      // next-p loads in flight...
    phase2(bufs[i & 1], p0 + i);           // ...while current p streams out
    if (i < 3) lds_write(bufs[(i + 1) & 1]);
    __syncthreads();
  }
}

// ---------------------------------------------------------------------------
// Batched NT GEMM body: per h, C[256][512] = A[256][512]*B[512][512]^T (bf16)
// Layouts (row stride RS_). 128x128 tile, 4 waves, BK=64, double-buffered
// global_load_lds staging with chunk-XOR swizzle via pre-swizzled source.
// gblk in [0,512): wkid = (gblk&7)*64 + (gblk>>3) colocates same-h on XCD.
// Epilogue: bf16 C + per-channel sum/sumsq atomics.
// BN_A: A gets y = relu(a1[k]*a + c1[k]) from sum_in/sq_in on the fly.
// ---------------------------------------------------------------------------
template <bool BN_A>
__device__ __forceinline__ void gemm_body(
    const __bf16* __restrict__ A, const __bf16* __restrict__ B,
    __bf16* __restrict__ Co,
    const float* __restrict__ sum_in, const float* __restrict__ sq_in,
    const float* __restrict__ g, const float* __restrict__ bb,
    float* __restrict__ sum_out, float* __restrict__ sq_out,
    int gblk, int tid, __bf16* AsB, __bf16* BsB,
    float* a_lds, float* c_lds) {
  const int wkid = (gblk & 7) * 64 + (gblk >> 3);
  const int h  = wkid >> 3;
  const int tm = (wkid >> 2) & 1, tn = wkid & 3;
  const int m0 = tm * 128, n0 = tn * 128;
  const __bf16* Ah = A + (size_t)m0 * RS_ + (size_t)h * C_;
  const __bf16* Bh = B + (size_t)n0 * RS_ + (size_t)h * C_;
  const int lane = tid & 63, wid = tid >> 6;
  const int wr = wid >> 1, wc = wid & 1;
  const int lrow8 = lane >> 3;
  const int swz   = (lane & 7) ^ lrow8;

  if (BN_A) {
#pragma unroll
    for (int ch = tid; ch < 512; ch += 256) {
      const float m    = sum_in[ch] * (1.f / 16384.f);
      const float var  = fmaxf(0.f, sq_in[ch] * (1.f / 16384.f) - m * m);
      const float aa   = g[ch] * rsqrtf(var + 1e-5f);
      a_lds[ch] = aa;
      c_lds[ch] = bb[ch] - m * aa;
    }
    __syncthreads();
  }

  auto stage_b = [&](int buf, int kt) {
#pragma unroll
    for (int i = 0; i < 4; ++i) {
      const int rbase = wid * 32 + i * 8;
      const __bf16* gb = Bh + (size_t)(rbase + lrow8) * RS_ + kt * 64 + swz * 8;
      __builtin_amdgcn_global_load_lds(
          (const __attribute__((address_space(1))) void*)gb,
          (__attribute__((address_space(3))) void*)(BsB + buf * 8192 + rbase * 64),
          16, 0, 0);
    }
  };
  auto stage_a = [&](int buf, int kt) {
#pragma unroll
    for (int i = 0; i < 4; ++i) {
      const int rbase = wid * 32 + i * 8;
      const __bf16* ga = Ah + (size_t)(rbase + lrow8) * RS_ + kt * 64 + swz * 8;
      __builtin_amdgcn_global_load_lds(
          (const __attribute__((address_space(1))) void*)ga,
          (__attribute__((address_space(3))) void*)(AsB + buf * 8192 + rbase * 64),
          16, 0, 0);
    }
  };
  const int lr32 = tid >> 3, cch = tid & 7;
  auto load_a = [&](bf16x8* v, int kt) {
#pragma unroll
    for (int i = 0; i < 4; ++i)
      v[i] = *reinterpret_cast<const bf16x8*>(
          Ah + (size_t)(i * 32 + lr32) * RS_ + kt * 64 + cch * 8);
  };
  auto bn_write = [&](const bf16x8* v, int buf, int kt) {
    const int cg = kt * 64 + cch * 8;
    const f32x4 s0 = *reinterpret_cast<const f32x4*>(&a_lds[cg]);
    const f32x4 s1 = *reinterpret_cast<const f32x4*>(&a_lds[cg + 4]);
    const f32x4 h0 = *reinterpret_cast<const f32x4*>(&c_lds[cg]);
    const f32x4 h1 = *reinterpret_cast<const f32x4*>(&c_lds[cg + 4]);
#pragma unroll
    for (int i = 0; i < 4; ++i) {
      const int row = i * 32 + lr32;
      bf16x8 y;
#pragma unroll
      for (int e = 0; e < 4; ++e) {
        y[e]     = (__bf16)fmaxf(0.f, fmaf((float)v[i][e],     s0[e], h0[e]));
        y[e + 4] = (__bf16)fmaxf(0.f, fmaf((float)v[i][e + 4], s1[e], h1[e]));
      }
      const int boff = row * 128 + ((cch * 16) ^ ((row & 7) << 4));
      *reinterpret_cast<bf16x8*>(reinterpret_cast<char*>(AsB + buf * 8192) + boff) = y;
    }
  };

  f32x4 acc[4][4] = {};
  const int fr = lane & 15, kc = lane >> 4;
  auto compute = [&](int buf) {
#pragma unroll
    for (int kk = 0; kk < 2; ++kk) {
      bf16x8 af[4], bfq[4];
#pragma unroll
      for (int mf = 0; mf < 4; ++mf) {
        const int row  = wr * 64 + mf * 16 + fr;
        const int boff = row * 128 + ((kk * 64 + kc * 16) ^ ((row & 7) << 4));
        af[mf] = *reinterpret_cast<const bf16x8*>(
            reinterpret_cast<const char*>(AsB + buf * 8192) + boff);
      }
#pragma unroll
      for (int nf = 0; nf < 4; ++nf) {
        const int row  = wc * 64 + nf * 16 + fr;
        const int boff = row * 128 + ((kk * 64 + kc * 16) ^ ((row & 7) << 4));
        bfq[nf] = *reinterpret_cast<const bf16x8*>(
            reinterpret_cast<const char*>(BsB + buf * 8192) + boff);
      }
#pragma unroll
      for (int mf = 0; mf < 4; ++mf)
#pragma unroll
        for (int nf = 0; nf < 4; ++nf)
          acc[mf][nf] = __builtin_amdgcn_mfma_f32_16x16x32_bf16(af[mf], bfq[nf], acc[mf][nf], 0, 0, 0);
    }
  };

  if (BN_A) {
    bf16x8 v0[4];
    load_a(v0, 0);
    bn_write(v0, 0, 0);
  } else {
    stage_a(0, 0);
  }
  stage_b(0, 0);
  __syncthreads();

  int buf = 0;
  for (int kt = 0; kt < 8; ++kt) {
    bf16x8 vn[4];
    if (kt < 7) {
      stage_b(buf ^ 1, kt + 1);
      if (!BN_A) stage_a(buf ^ 1, kt + 1);
      else       load_a(vn, kt + 1);
    }
    compute(buf);
    if (BN_A && kt < 7) bn_write(vn, buf ^ 1, kt + 1);
    __syncthreads();
    buf ^= 1;
  }

  const int rq = (lane >> 4) * 4;
#pragma unroll
  for (int nf = 0; nf < 4; ++nf) {
    const int oc = n0 + wc * 64 + nf * 16 + fr;
    float s = 0.f, s2 = 0.f;
#pragma unroll
    for (int mf = 0; mf < 4; ++mf) {
      const int rb = m0 + wr * 64 + mf * 16 + rq;
      f32x4 v = acc[mf][nf];
#pragma unroll
      for (int j = 0; j < 4; ++j) {
        const float f = v[j];
        Co[(size_t)(rb + j) * RS_ + (size_t)h * C_ + oc] = (__bf16)f;
        s += f;
        s2 += f * f;
      }
    }
    s  += __shfl_xor(s, 16);  s  += __shfl_xor(s, 32);
    s2 += __shfl_xor(s2, 16); s2 += __shfl_xor(s2, 32);
    if (lane < 16) {
      atomicAdd(&sum_out[oc], s);
      atomicAdd(&sq_out[oc], s2);
    }
  }
}

// ---------------------------------------------------------------------------
// K1: pipelined prep of x (blocks 0..255) and w1 (blocks 256..767).
// Block 0 also zeroes the BN stat accumulators.
// ---------------------------------------------------------------------------
__global__ __launch_bounds__(256) void k_prep_xw1(const float* __restrict__ x,
                                                  const float* __restrict__ w1,
                                                  __bf16* __restrict__ xT,
                                                  __bf16* __restrict__ w1T,
                                                  float* __restrict__ stats) {
  __shared__ uint32_t lds[2 * 128 * 32];
  const int bid = blockIdx.x, t = threadIdx.x;
  if (bid == 0) {
#pragma unroll
    for (int i = 0; i < 8; ++i) stats[i * 256 + t] = 0.f;
  }
  const bool isx = bid < 256;
  const float* src = isx ? x : w1;
  __bf16* dst = isx ? xT : w1T;
  const int b = isx ? bid : bid - 256;
  prep_tile4(src, dst, b >> 2, b & 3, t, lds);
}

// ---------------------------------------------------------------------------
// K2: co-dispatch of GEMM1 (512 blocks) + prep of w2 (512 pipelined blocks).
// Role: (bid&15)<8 -> gemm, else prep; sub-id = (bid>>4)*8 + (bid&7) keeps
// the gemm XCD-locality property (sub%8 == bid%8 == XCD).
// Shared 64 KB LDS union -> 2 blocks/CU, typically one of each role.
// ---------------------------------------------------------------------------
__global__ __launch_bounds__(256, 2) void k_gemm1_prepw2(
    const __bf16* __restrict__ xT, const __bf16* __restrict__ w1T,
    __bf16* __restrict__ t1T,
    float* __restrict__ sum1, float* __restrict__ sq1,
    const float* __restrict__ w2, __bf16* __restrict__ w2T) {
  __shared__ __align__(16) char smem[65536];
  const int bid = blockIdx.x, t = threadIdx.x;
  const int sub = (bid >> 4) * 8 + (bid & 7);
  if ((bid & 15) < 8) {
    gemm_body<false>(xT, w1T, t1T, nullptr, nullptr, nullptr, nullptr,
                     sum1, sq1, sub, t,
                     (__bf16*)smem, (__bf16*)(smem + 32768), nullptr, nullptr);
  } else {
    prep_tile4(w2, w2T, sub >> 2, sub & 3, t, (uint32_t*)smem);
  }
}

// ---------------------------------------------------------------------------
// K3: GEMM2 with fused BN1+ReLU on A.
// ---------------------------------------------------------------------------
__global__ __launch_bounds__(256, 2) void k_gemm2(
    const __bf16* __restrict__ t1T, const __bf16* __restrict__ w2T,
    __bf16* __restrict__ t2T,
    const float* __restrict__ sum1, const float* __restrict__ sq1,
    const float* __restrict__ g1, const float* __restrict__ b1,
    float* __restrict__ sum2, float* __restrict__ sq2) {
  __shared__ __bf16 As[2][8192];
  __shared__ __bf16 Bs[2][8192];
  __shared__ float a_lds[512], c_lds[512];
  gemm_body<true>(t1T, w2T, t2T, sum1, sq1, g1, b1, sum2, sq2,
                  (int)blockIdx.x, (int)threadIdx.x,
                  &As[0][0], &Bs[0][0], a_lds, c_lds);
}

// ---------------------------------------------------------------------------
// K4: out[n][o][h] = relu(a2[o]*t2[n][h][o] + c2[o] + x[n][o][h])
// t2 layout (N, H, C); a2/c2 computed per block from sum2/sq2.
// ---------------------------------------------------------------------------
__global__ __launch_bounds__(256) void k_finalize(const __bf16* __restrict__ t2,
                                                  const float* __restrict__ x,
                                                  const float* __restrict__ sum2,
                                                  const float* __restrict__ sq2,
                                                  const float* __restrict__ g2,
                                                  const float* __restrict__ b2,
                                                  float* __restrict__ out) {
  __shared__ float tile[64][65];
  __shared__ float a2s[64], c2s[64];
  const int n  = blockIdx.y;
  const int o0 = blockIdx.x * 64;
  const int t  = threadIdx.x;
  if (t < 64) {
    const int o = o0 + t;
    const float m    = sum2[o] * (1.f / 16384.f);
    const float var  = fmaxf(0.f, sq2[o] * (1.f / 16384.f) - m * m);
    const float a    = g2[o] * rsqrtf(var + 1e-5f);
    a2s[t] = a;
    c2s[t] = b2[o] - m * a;
  }
  const __bf16* tb = t2 + (size_t)n * RS_ + o0;
#pragma unroll
  for (int j = 0; j < 4; ++j) {
    const int hh = j * 16 + (t >> 4);
    const int ol = (t & 15) * 4;
    const bf16x4 v = *reinterpret_cast<const bf16x4*>(tb + (size_t)hh * 512 + ol);
#pragma unroll
    for (int e = 0; e < 4; ++e) tile[hh][ol + e] = (float)v[e];
  }
  __syncthreads();
  const int ol = t >> 2;
  const int hb = (t & 3) * 16;
  const int o  = o0 + ol;
  const float a = a2s[ol], c = c2s[ol];
  const float4* xp = reinterpret_cast<const float4*>(x + ((size_t)n * C_ + o) * H_ + hb);
  float4* op = reinterpret_cast<float4*>(out + ((size_t)n * C_ + o) * H_ + hb);
#pragma unroll
  for (int i4 = 0; i4 < 4; ++i4) {
    const float4 xv = xp[i4];
    float4 r;
    r.x = fmaxf(0.f, fmaf(a, tile[hb + i4 * 4 + 0][ol], c) + xv.x);
    r.y = fmaxf(0.f, fmaf(a, tile[hb + i4 * 4 + 1][ol], c) + xv.y);
    r.z = fmaxf(0.f, fmaf(a, tile[hb + i4 * 4 + 2][ol], c) + xv.z);
    r.w = fmaxf(0.f, fmaf(a, tile[hb + i4 * 4 + 3][ol], c) + xv.w);
    op[i4] = r;
  }
}

// ---------------------------------------------------------------------------
extern "C" void kernel_launch(void* const* d_in, const int* in_sizes, int n_in,
                              void* d_out, int out_size, void* d_ws, size_t ws_size,
                              hipStream_t stream) {
  const float* x  = (const float*)d_in[0];
  const float* w1 = (const float*)d_in[1];
  const float* g1 = (const float*)d_in[2];
  const float* b1 = (const float*)d_in[3];
  const float* w2 = (const float*)d_in[4];
  const float* g2 = (const float*)d_in[5];
  const float* b2 = (const float*)d_in[6];
  float* out = (float*)d_out;

  char* ws = (char*)d_ws;
  float* stats = (float*)ws;  // sum1, sq1, sum2, sq2
  float* sum1 = stats,        *sq1 = stats + 512;
  float* sum2 = stats + 1024, *sq2 = stats + 1536;
  const size_t MB = (size_t)1 << 20;
  __bf16* xT  = (__bf16*)(ws + 64 * 1024);
  __bf16* w1T = (__bf16*)(ws + 64 * 1024 + 16 * MB);
  __bf16* w2T = (__bf16*)(ws + 64 * 1024 + 48 * MB);
  __bf16* t1T = (__bf16*)(ws + 64 * 1024 + 80 * MB);
  __bf16* t2T = (__bf16*)(ws + 64 * 1024 + 96 * MB);

  k_prep_xw1<<<768, 256, 0, stream>>>(x, w1, xT, w1T, stats);
  k_gemm1_prepw2<<<1024, 256, 0, stream>>>(xT, w1T, t1T, sum1, sq1, w2, w2T);
  k_gemm2<<<512, 256, 0, stream>>>(t1T, w2T, t2T, sum1, sq1, g1, b1, sum2, sq2);
  k_finalize<<<dim3(8, 256), 256, 0, stream>>>(t2T, x, sum2, sq2, g2, b2, out);
}